// Round 2
// baseline (292.271 us; speedup 1.0000x reference)
//
#include <hip/hip_runtime.h>

typedef _Float16 f16;
typedef __attribute__((ext_vector_type(8))) _Float16 f16x8;
typedef __attribute__((ext_vector_type(4))) float f32x4;
typedef unsigned int u32;

#define S_      4
#define NPER    12500
#define NF      1024
#define HID     256
#define NSTRUCT 500
#define TM      64

#define GLB __attribute__((address_space(1)))
#define AS3 __attribute__((address_space(3)))

#define WAIT_VM(N)  asm volatile("s_waitcnt vmcnt(" #N ")" ::: "memory")
#define WAIT_LGKM() asm volatile("s_waitcnt lgkmcnt(0)" ::: "memory")
#define SCHED0()    __builtin_amdgcn_sched_barrier(0)
#define BARRIER()   do { __builtin_amdgcn_s_barrier(); SCHED0(); } while (0)

// ---------------------------------------------------------------------------
// Fused weight transpose + fp32->fp16 (all 3 layers, 1 launch) -- unchanged.
// ---------------------------------------------------------------------------
__global__ __launch_bounds__(256) void transpose_all_kernel(
    const float* __restrict__ W1, const float* __restrict__ W2,
    const float* __restrict__ W3,
    f16* __restrict__ w1t, f16* __restrict__ w2t, f16* __restrict__ w3t)
{
  const int z = blockIdx.z;            // layer*4 + species
  const int layer = z >> 2, sp = z & 3;
  const float* in; f16* out; int K;
  if (layer == 0)      { in = W1; out = w1t; K = NF;  }
  else if (layer == 1) { in = W2; out = w2t; K = HID; }
  else                 { in = W3; out = w3t; K = HID; }
  if (blockIdx.x * 64 >= K) return;

  __shared__ float tile[64][65];
  const float* inp = in + (size_t)sp * K * HID;
  f16* outp = out + (size_t)sp * K * HID;
  const int k0 = blockIdx.x * 64;
  const int n0 = blockIdx.y * 64;
  const int t = threadIdx.x;
  {
    const int lk = t >> 2;
    const int nq = (t & 3) * 16;
    const float* src = inp + (size_t)(k0 + lk) * HID + n0 + nq;
    #pragma unroll
    for (int i = 0; i < 4; ++i) {
      float4 v = *(const float4*)(src + i * 4);
      tile[lk][nq + i * 4 + 0] = v.x;
      tile[lk][nq + i * 4 + 1] = v.y;
      tile[lk][nq + i * 4 + 2] = v.z;
      tile[lk][nq + i * 4 + 3] = v.w;
    }
  }
  __syncthreads();
  {
    const int ln = t >> 2;
    const int kq = (t & 3) * 16;
    f16* dst = outp + (size_t)(n0 + ln) * K + k0 + kq;
    f16x8 a, b;
    #pragma unroll
    for (int j = 0; j < 8; ++j) a[j] = (f16)tile[kq + j][ln];
    #pragma unroll
    for (int j = 0; j < 8; ++j) b[j] = (f16)tile[kq + 8 + j][ln];
    *(f16x8*)dst = a;
    *(f16x8*)(dst + 8) = b;
  }
}

// ---------------------------------------------------------------------------
// Fused MLP R9: KC=32, quad-buffered fp32 A (gll), B in regs, 32 KB LDS.
//  - Cross-wave drain rule: A(c+1) must be vm-drained by ALL waves before the
//    barrier ending phase c.  Quad buffer => A(c+1) was ISSUED at phase c-2
//    => 2 full phases of HBM cover (R8's tri-buffer only gave 1).
//  - Steady phase: issue B(c+1) [4 loads] then A(c+3) [2 gll]; in-flight at
//    wait = A(c+1)2,B(c)4,A(c+2)2,B(c+1)4,A(c+3)2 = 14 -> VM(8) drains
//    exactly A(c+1)+B(c).
//  - Hidden layers: barrier-free, B reg-dbuf, compiler-managed waits.
//  - Arena 32 KB (4x8KB A quad; hL 32 KB overlays) + bounds(256,4):
//    target 4 blocks/CU = 16 waves/CU.
// ---------------------------------------------------------------------------

__device__ __forceinline__ void zero_acc(f32x4 (&acc)[4][4]) {
  #pragma unroll
  for (int a = 0; a < 4; ++a)
    #pragma unroll
    for (int b = 0; b < 4; ++b)
      #pragma unroll
      for (int j = 0; j < 4; ++j) acc[a][b][j] = 0.f;
}

// B fragments L2 -> regs: 4 x 16B per lane per KC=32 chunk.
// frag bt: col nn = w*64+bt*16+l15, k = c*32 + g*8 .. +7.
__device__ __forceinline__ void load_b32(f16x8 (&bf)[4], const f16* wsrc, int c,
                                         int K, int w, int g, int l15)
{
  #pragma unroll
  for (int bt = 0; bt < 4; ++bt) {
    const int nn = w * 64 + bt * 16 + l15;
    bf[bt] = *(const f16x8*)(wsrc + (size_t)nn * K + c * 32 + g * 8);
  }
}

// L1 compute: one KC=32 chunk, fp32 A from LDS (convert on read), B regs.
// A row = 128 B = 8 slots of 16B; phys slot = logical ^ (row&7).
__device__ __forceinline__ void mfma32_a(f32x4 (&acc)[4][4], const char* aS,
                                         const f16x8 (&bf)[4], int g, int l15)
{
  f16x8 af[4];
  #pragma unroll
  for (int at = 0; at < 4; ++at) {
    const int rr = at * 16 + l15;
    const int sw = rr & 7;
    const f32x4 lo = *(const f32x4*)(aS + rr * 128 + (((g * 2)     ^ sw) << 4));
    const f32x4 hi = *(const f32x4*)(aS + rr * 128 + (((g * 2 + 1) ^ sw) << 4));
    f16x8 a;
    a[0]=(f16)lo[0]; a[1]=(f16)lo[1]; a[2]=(f16)lo[2]; a[3]=(f16)lo[3];
    a[4]=(f16)hi[0]; a[5]=(f16)hi[1]; a[6]=(f16)hi[2]; a[7]=(f16)hi[3];
    af[at] = a;
  }
  #pragma unroll
  for (int at = 0; at < 4; ++at)
    #pragma unroll
    for (int bt = 0; bt < 4; ++bt)
      acc[at][bt] = __builtin_amdgcn_mfma_f32_16x16x32_f16(af[at], bf[bt], acc[at][bt], 0, 0, 0);
}

// Hidden compute: KC=32 chunk, A = hL fp16 (xor (row&7)<<4 layout), B regs.
__device__ __forceinline__ void mfma32_h(f32x4 (&acc)[4][4], const char* hL, int cH,
                                         const f16x8 (&bf)[4], int g, int l15)
{
  f16x8 af[4];
  #pragma unroll
  for (int at = 0; at < 4; ++at) {
    const int rr = at * 16 + l15;
    af[at] = *(const f16x8*)(hL + ((rr * 512 + cH * 64 + g * 16) ^ ((rr & 7) << 4)));
  }
  #pragma unroll
  for (int at = 0; at < 4; ++at)
    #pragma unroll
    for (int bt = 0; bt < 4; ++bt)
      acc[at][bt] = __builtin_amdgcn_mfma_f32_16x16x32_f16(af[at], bf[bt], acc[at][bt], 0, 0, 0);
}

__device__ __forceinline__ void silu_store(f32x4 (&acc)[4][4],
                                           const float* __restrict__ bias,
                                           char* hL, int w, int lane)
{
  const int g = lane >> 4, l15 = lane & 15;
  #pragma unroll
  for (int bt = 0; bt < 4; ++bt) {
    const int col = w * 64 + bt * 16 + l15;
    const float b = bias[col];
    #pragma unroll
    for (int at = 0; at < 4; ++at) {
      #pragma unroll
      for (int j = 0; j < 4; ++j) {
        const int row = at * 16 + g * 4 + j;   // m89-verified C/D mapping
        float x = acc[at][bt][j] + b;
        x = x * __builtin_amdgcn_rcpf(1.f + __expf(-x));
        *(f16*)(hL + (((row * HID + col) * 2) ^ ((row & 7) << 4))) = (f16)x;
      }
    }
  }
}

// A quad-buffer select (8 KB each)
#define ASB(c) (arena + (((c) & 3) << 13))

// Stage one KC=32 A chunk: wave w stages rows w*16..+15 (2 gll of 8 rows).
// Linear LDS dest (HW adds lane*16 -> rowlocal*128 + p*16); source slot
// pre-swizzled: slog = (lane&7) ^ (row&7)  (same involution as read side).
#define STAGE_A(buf, c)                                                        \
  do {                                                                         \
    __builtin_amdgcn_global_load_lds((const GLB u32*)(agp0 + (size_t)(c) * 32),\
                                     (AS3 u32*)((buf) + aoff), 16, 0, 0);      \
    __builtin_amdgcn_global_load_lds((const GLB u32*)(agp1 + (size_t)(c) * 32),\
                                     (AS3 u32*)((buf) + aoff + 1024), 16, 0, 0);\
  } while (0)

// Steady L1 phase: B(c+1) -> regs, A(c+3) -> gll, counted wait, compute c.
#define L1_PH(c, BFcur, BFnxt, DOA, DOB, VMN)                 \
  do {                                                         \
    if (DOB) load_b32(BFnxt, w1s, (c) + 1, NF, w, g, l15);     \
    if (DOA) STAGE_A(ASB((c) + 3), (c) + 3);                   \
    WAIT_VM(VMN); SCHED0();                                    \
    mfma32_a(acc, ASB(c), BFcur, g, l15);                      \
    WAIT_LGKM(); BARRIER();                                    \
  } while (0)

__global__ __launch_bounds__(256, 4) void mlp_fused_kernel(
    const float* __restrict__ feats,
    const float* __restrict__ b1g,
    const float* __restrict__ b2g,
    const float* __restrict__ b3g,
    const float* __restrict__ w4g,
    const float* __restrict__ b4g,
    const int*   __restrict__ sidxg,
    const f16*   __restrict__ w1t,
    const f16*   __restrict__ w2t,
    const f16*   __restrict__ w3t,
    float*       __restrict__ outg)
{
  __shared__ char arena[32 * 1024];
  char* hL = arena;                  // hidden: h [64][256] fp16, 32 KB overlay

  const int s    = blockIdx.y;
  const int row0 = blockIdx.x * TM;
  const int t    = threadIdx.x;
  const int lane = t & 63;
  const int w    = t >> 6;           // 0..3; wave w owns output cols w*64..+63
  const int g    = lane >> 4;
  const int l15  = lane & 15;

  const int gr   = row0 + (t >> 2);
  const bool valid = gr < NPER;
  const float* fbase = feats + (size_t)s * NPER * NF;
  const f16*   w1s   = w1t + (size_t)s * HID * NF;
  const f16*   w2s   = w2t + (size_t)s * HID * HID;
  const f16*   w3s   = w3t + (size_t)s * HID * HID;

  // Precomputed per-lane A staging sources (advance by c*32 floats per chunk)
  const int arow0l = w * 16 + (lane >> 3);
  const int arow1l = arow0l + 8;
  int rg0 = row0 + arow0l; if (rg0 > NPER - 1) rg0 = NPER - 1;
  int rg1 = row0 + arow1l; if (rg1 > NPER - 1) rg1 = NPER - 1;
  const float* agp0 = fbase + (size_t)rg0 * NF + (((lane & 7) ^ (arow0l & 7)) << 2);
  const float* agp1 = fbase + (size_t)rg1 * NF + (((lane & 7) ^ (arow1l & 7)) << 2);
  const u32 aoff = (u32)(w * 16) << 7;   // wave-uniform LDS base offset

  f32x4 acc[4][4];
  f16x8 bfA[4], bfB[4];
  zero_acc(acc);

  // ===== L1 prologue: A0,A1,A2 staged (6 gll); B0 in flight (4) =====
  STAGE_A(ASB(0), 0);
  STAGE_A(ASB(1), 1);
  STAGE_A(ASB(2), 2);
  load_b32(bfA, w1s, 0, NF, w, g, l15);
  WAIT_VM(8); SCHED0();              // drain own A(0) (leaves A1,A2,B0)
  BARRIER();                         // A(0) globally visible

  // ===== L1: 32 phases, KC=32, quad-buffered A, reg-dbuf B =====
  L1_PH(0, bfA, bfB, 1, 1, 6);       // drains A1,A2,B0 (one-time over-drain)
  L1_PH(1, bfB, bfA, 1, 1, 8);       // drains B1
  for (int c = 2; c <= 27; c += 2) { // steady: drains A(c+1), B(c)
    L1_PH(c,     bfA, bfB, 1, 1, 8);
    L1_PH(c + 1, bfB, bfA, 1, 1, 8);
  }
  L1_PH(28, bfA, bfB, 1, 1, 8);      // stages A(31)
  L1_PH(29, bfB, bfA, 0, 1, 6);      // drains A(30), B(29)
  L1_PH(30, bfA, bfB, 0, 1, 4);      // drains A(31), B(30)
  { // phase 31: drain B(31); early-issue W2 chunk 0 into bfA
    WAIT_VM(0); SCHED0();
    mfma32_a(acc, ASB(31), bfB, g, l15);
    load_b32(bfA, w2s, 0, HID, w, g, l15);
    WAIT_LGKM(); BARRIER();
  }

  // ===== L1 -> L2: write h over dead A buffers =====
  silu_store(acc, b1g + s * HID, hL, w, lane);
  zero_acc(acc);
  WAIT_LGKM(); BARRIER();

  // ===== Layer 2: 8 chunks KC=32, barrier-free, reg-dbuf B =====
  load_b32(bfB, w2s, 1, HID, w, g, l15);  mfma32_h(acc, hL, 0, bfA, g, l15);
  load_b32(bfA, w2s, 2, HID, w, g, l15);  mfma32_h(acc, hL, 1, bfB, g, l15);
  load_b32(bfB, w2s, 3, HID, w, g, l15);  mfma32_h(acc, hL, 2, bfA, g, l15);
  load_b32(bfA, w2s, 4, HID, w, g, l15);  mfma32_h(acc, hL, 3, bfB, g, l15);
  load_b32(bfB, w2s, 5, HID, w, g, l15);  mfma32_h(acc, hL, 4, bfA, g, l15);
  load_b32(bfA, w2s, 6, HID, w, g, l15);  mfma32_h(acc, hL, 5, bfB, g, l15);
  load_b32(bfB, w2s, 7, HID, w, g, l15);  mfma32_h(acc, hL, 6, bfA, g, l15);
  load_b32(bfA, w3s, 0, HID, w, g, l15);  mfma32_h(acc, hL, 7, bfB, g, l15);
  BARRIER();                         // all waves done reading hL
  silu_store(acc, b2g + s * HID, hL, w, lane);
  zero_acc(acc);
  WAIT_LGKM(); BARRIER();            // hL published

  // ===== Layer 3: 8 chunks, barrier-free =====
  load_b32(bfB, w3s, 1, HID, w, g, l15);  mfma32_h(acc, hL, 0, bfA, g, l15);
  load_b32(bfA, w3s, 2, HID, w, g, l15);  mfma32_h(acc, hL, 1, bfB, g, l15);
  load_b32(bfB, w3s, 3, HID, w, g, l15);  mfma32_h(acc, hL, 2, bfA, g, l15);
  load_b32(bfA, w3s, 4, HID, w, g, l15);  mfma32_h(acc, hL, 3, bfB, g, l15);
  load_b32(bfB, w3s, 5, HID, w, g, l15);  mfma32_h(acc, hL, 4, bfA, g, l15);
  load_b32(bfA, w3s, 6, HID, w, g, l15);  mfma32_h(acc, hL, 5, bfB, g, l15);
  load_b32(bfB, w3s, 7, HID, w, g, l15);  mfma32_h(acc, hL, 6, bfA, g, l15);
                                          mfma32_h(acc, hL, 7, bfB, g, l15);
  BARRIER();
  silu_store(acc, b3g + s * HID, hL, w, lane);
  WAIT_LGKM(); BARRIER();

  // ===== Layer 4: e = h @ W4 + b4; segment-sum via atomicAdd =====
  {
    const int row = t >> 2;
    const int q   = t & 3;
    const float* w4 = w4g + s * HID;
    float sum = 0.f;
    #pragma unroll
    for (int j8 = 0; j8 < 64; j8 += 8) {
      const int k = q * 64 + j8;
      f16x8 hv = *(const f16x8*)(hL + (((row * HID + k) * 2) ^ ((row & 7) << 4)));
      float4 wa = *(const float4*)(w4 + k);
      float4 wb = *(const float4*)(w4 + k + 4);
      sum += (float)hv[0] * wa.x + (float)hv[1] * wa.y + (float)hv[2] * wa.z + (float)hv[3] * wa.w
           + (float)hv[4] * wb.x + (float)hv[5] * wb.y + (float)hv[6] * wb.z + (float)hv[7] * wb.w;
    }
    sum += __shfl_xor(sum, 1);
    sum += __shfl_xor(sum, 2);
    if (q == 0 && valid) {
      atomicAdd(&outg[sidxg[s * NPER + gr]], sum + b4g[s]);
    }
  }
}

// ---------------------------------------------------------------------------
extern "C" void kernel_launch(void* const* d_in, const int* in_sizes, int n_in,
                              void* d_out, int out_size, void* d_ws, size_t ws_size,
                              hipStream_t stream)
{
  const float* feats = (const float*)d_in[0];
  const float* W1    = (const float*)d_in[1];
  const float* b1    = (const float*)d_in[2];
  const float* W2    = (const float*)d_in[3];
  const float* b2    = (const float*)d_in[4];
  const float* W3    = (const float*)d_in[5];
  const float* b3    = (const float*)d_in[6];
  const float* W4    = (const float*)d_in[7];
  const float* b4    = (const float*)d_in[8];
  const int*   sidx  = (const int*)d_in[9];
  float* out = (float*)d_out;

  f16* w1t = (f16*)d_ws;                              // [S][256][1024] fp16
  f16* w2t = w1t + (size_t)S_ * HID * NF;             // [S][256][256]  fp16
  f16* w3t = w2t + (size_t)S_ * HID * HID;            // [S][256][256]  fp16

  hipMemsetAsync(d_out, 0, NSTRUCT * sizeof(float), stream);
  transpose_all_kernel<<<dim3(16, 4, 12), 256, 0, stream>>>(W1, W2, W3, w1t, w2t, w3t);
  mlp_fused_kernel<<<dim3((NPER + TM - 1) / TM, S_), 256, 0, stream>>>(
      feats, b1, b2, b3, W4, b4, sidx, w1t, w2t, w3t, out);
}

// Round 3
// 142.601 us; speedup vs baseline: 2.0496x; 2.0496x over previous
//
#include <hip/hip_runtime.h>

typedef _Float16 f16;
typedef __attribute__((ext_vector_type(8))) _Float16 f16x8;
typedef __attribute__((ext_vector_type(4))) float f32x4;
typedef unsigned int u32;

#define S_      4
#define NPER    12500
#define NF      1024
#define HID     256
#define NSTRUCT 500
#define TM      64

#define WAIT_LGKM() asm volatile("s_waitcnt lgkmcnt(0)" ::: "memory")
#define SCHED0()    __builtin_amdgcn_sched_barrier(0)
#define BARRIER()   do { __builtin_amdgcn_s_barrier(); SCHED0(); } while (0)

// ---------------------------------------------------------------------------
// Fused weight transpose + fp32->fp16 (all 3 layers, 1 launch) -- unchanged.
// ---------------------------------------------------------------------------
__global__ __launch_bounds__(256) void transpose_all_kernel(
    const float* __restrict__ W1, const float* __restrict__ W2,
    const float* __restrict__ W3,
    f16* __restrict__ w1t, f16* __restrict__ w2t, f16* __restrict__ w3t)
{
  const int z = blockIdx.z;            // layer*4 + species
  const int layer = z >> 2, sp = z & 3;
  const float* in; f16* out; int K;
  if (layer == 0)      { in = W1; out = w1t; K = NF;  }
  else if (layer == 1) { in = W2; out = w2t; K = HID; }
  else                 { in = W3; out = w3t; K = HID; }
  if (blockIdx.x * 64 >= K) return;

  __shared__ float tile[64][65];
  const float* inp = in + (size_t)sp * K * HID;
  f16* outp = out + (size_t)sp * K * HID;
  const int k0 = blockIdx.x * 64;
  const int n0 = blockIdx.y * 64;
  const int t = threadIdx.x;
  {
    const int lk = t >> 2;
    const int nq = (t & 3) * 16;
    const float* src = inp + (size_t)(k0 + lk) * HID + n0 + nq;
    #pragma unroll
    for (int i = 0; i < 4; ++i) {
      float4 v = *(const float4*)(src + i * 4);
      tile[lk][nq + i * 4 + 0] = v.x;
      tile[lk][nq + i * 4 + 1] = v.y;
      tile[lk][nq + i * 4 + 2] = v.z;
      tile[lk][nq + i * 4 + 3] = v.w;
    }
  }
  __syncthreads();
  {
    const int ln = t >> 2;
    const int kq = (t & 3) * 16;
    f16* dst = outp + (size_t)(n0 + ln) * K + k0 + kq;
    f16x8 a, b;
    #pragma unroll
    for (int j = 0; j < 8; ++j) a[j] = (f16)tile[kq + j][ln];
    #pragma unroll
    for (int j = 0; j < 8; ++j) b[j] = (f16)tile[kq + 8 + j][ln];
    *(f16x8*)dst = a;
    *(f16x8*)(dst + 8) = b;
  }
}

// ---------------------------------------------------------------------------
// Fused MLP R10 = proven-best recombination:
//  - L1 A-path: R7's reg-staged deep prefetch (pa fp32 regs -> fp16 ds_write,
//    KC=64, 16 phases, proven conflict-free 8-slot XOR layout).
//  - B-path: R8's L2->registers dbuf (no LDS B, no gll at all in this kernel).
//  - NO manual vmcnt anywhere: compiler emits per-register counted waits
//    (vmcnt(12) before ds_write of pa, vmcnt(16) before MFMA's B use) which
//    exactly reproduce R7's manual discipline without over-draining.
//  - Sync per L1 phase: WAIT_LGKM + barrier only (A tile is cross-wave shared).
//  - Hidden layers: barrier-free, reg-dbuf B, KC=64 (R8/R9-proven).
//  - Arena 32 KB (A dbuf 2x8KB fp16; hL 32KB overlays).
// ---------------------------------------------------------------------------

__device__ __forceinline__ void zero_acc(f32x4 (&acc)[4][4]) {
  #pragma unroll
  for (int a = 0; a < 4; ++a)
    #pragma unroll
    for (int b = 0; b < 4; ++b)
      #pragma unroll
      for (int j = 0; j < 4; ++j) acc[a][b][j] = 0.f;
}

// B fragments L2 -> regs: 8 x 16B per lane per KC=64 chunk.
// frag(ks,bt): col nn = w*64+bt*16+l15, k = c*64 + (ks*4+g)*8 .. +7.
__device__ __forceinline__ void load_b64(f16x8 (&bf)[8], const f16* wsrc, int c,
                                         int K, int w, int g, int l15)
{
  #pragma unroll
  for (int ks = 0; ks < 2; ++ks)
    #pragma unroll
    for (int bt = 0; bt < 4; ++bt) {
      const int nn = w * 64 + bt * 16 + l15;
      bf[ks * 4 + bt] = *(const f16x8*)(wsrc + (size_t)nn * K + c * 64 + (ks * 4 + g) * 8);
    }
}

__device__ __forceinline__ void load_pa(float4 (&pa)[4], const float* fsrcT, int c)
{
  #pragma unroll
  for (int j = 0; j < 4; ++j)
    pa[j] = *(const float4*)(fsrcT + c * 64 + j * 4);
}

// Features chunk [64 r][64 k] fp32->fp16 into aS. Row = 128B = 8 slots of
// 16B; phys slot p at row r holds logical k-slot p^(r&7). (R7-proven.)
__device__ __forceinline__ void stage_feat64(char* aS, const float4 (&pa)[4], int t)
{
  const int r = t >> 2;
  #pragma unroll
  for (int wr = 0; wr < 2; ++wr) {
    f16x8 hv;
    const float4 lo = pa[wr * 2 + 0], hi = pa[wr * 2 + 1];
    hv[0]=(f16)lo.x; hv[1]=(f16)lo.y; hv[2]=(f16)lo.z; hv[3]=(f16)lo.w;
    hv[4]=(f16)hi.x; hv[5]=(f16)hi.y; hv[6]=(f16)hi.z; hv[7]=(f16)hi.w;
    const int slog = (t & 3) * 2 + wr;
    const int p = slog ^ (r & 7);
    *(f16x8*)(aS + r * 128 + p * 16) = hv;
  }
}

// L1 compute: one KC=64 chunk, A from LDS (R7 layout), B regs. 32 MFMA.
__device__ __forceinline__ void mfma64_ab(f32x4 (&acc)[4][4], const char* aS,
                                          const f16x8 (&bf)[8], int g, int l15)
{
  #pragma unroll
  for (int ks = 0; ks < 2; ++ks) {
    f16x8 af[4];
    #pragma unroll
    for (int at = 0; at < 4; ++at) {
      const int rr = at * 16 + l15;
      const int p  = (ks * 4 + g) ^ (rr & 7);
      af[at] = *(const f16x8*)(aS + rr * 128 + p * 16);
    }
    #pragma unroll
    for (int at = 0; at < 4; ++at)
      #pragma unroll
      for (int bt = 0; bt < 4; ++bt)
        acc[at][bt] = __builtin_amdgcn_mfma_f32_16x16x32_f16(af[at], bf[ks*4+bt], acc[at][bt], 0, 0, 0);
  }
}

// Hidden compute: KC=64 chunk, A = hL fp16 (xor (row&7)<<4 layout), B regs.
__device__ __forceinline__ void mfma64_h(f32x4 (&acc)[4][4], const char* hL, int cH,
                                         const f16x8 (&bf)[8], int g, int l15)
{
  #pragma unroll
  for (int ks = 0; ks < 2; ++ks) {
    f16x8 af[4];
    #pragma unroll
    for (int at = 0; at < 4; ++at) {
      const int rr = at * 16 + l15;
      af[at] = *(const f16x8*)(hL + ((rr * 512 + cH * 128 + ks * 64 + g * 16) ^ ((rr & 7) << 4)));
    }
    #pragma unroll
    for (int at = 0; at < 4; ++at)
      #pragma unroll
      for (int bt = 0; bt < 4; ++bt)
        acc[at][bt] = __builtin_amdgcn_mfma_f32_16x16x32_f16(af[at], bf[ks*4+bt], acc[at][bt], 0, 0, 0);
  }
}

__device__ __forceinline__ void silu_store(f32x4 (&acc)[4][4],
                                           const float* __restrict__ bias,
                                           char* hL, int w, int lane)
{
  const int g = lane >> 4, l15 = lane & 15;
  #pragma unroll
  for (int bt = 0; bt < 4; ++bt) {
    const int col = w * 64 + bt * 16 + l15;
    const float b = bias[col];
    #pragma unroll
    for (int at = 0; at < 4; ++at) {
      #pragma unroll
      for (int j = 0; j < 4; ++j) {
        const int row = at * 16 + g * 4 + j;   // m89-verified C/D mapping
        float x = acc[at][bt][j] + b;
        x = x * __builtin_amdgcn_rcpf(1.f + __expf(-x));
        *(f16*)(hL + (((row * HID + col) * 2) ^ ((row & 7) << 4))) = (f16)x;
      }
    }
  }
}

// Steady L1 phase: stage A(c+1) from pa (fp16 ds_write), load B(c+1)->regs,
// refill pa with chunk c+3, compute chunk c (compiler-counted vm waits),
// lgkm-drain own ds ops, barrier.  Order: writes go to the OTHER buffer;
// reads of aS(cur) precede the barrier; next phase's writes to aS(cur)
// come after it -> WAR safe.
#define L1_PH(c, AScur, ASstg, BFcur, BFnxt, PAset, DOPA, DOB)  \
  do {                                                           \
    stage_feat64(ASstg, PAset, t);                               \
    if (DOB)  load_b64(BFnxt, w1s, (c) + 1, NF, w, g, l15);      \
    if (DOPA) load_pa(PAset, fsrcT, (c) + 3);                    \
    mfma64_ab(acc, AScur, BFcur, g, l15);                        \
    WAIT_LGKM(); BARRIER();                                      \
  } while (0)

__global__ __launch_bounds__(256, 2) void mlp_fused_kernel(
    const float* __restrict__ feats,
    const float* __restrict__ b1g,
    const float* __restrict__ b2g,
    const float* __restrict__ b3g,
    const float* __restrict__ w4g,
    const float* __restrict__ b4g,
    const int*   __restrict__ sidxg,
    const f16*   __restrict__ w1t,
    const f16*   __restrict__ w2t,
    const f16*   __restrict__ w3t,
    float*       __restrict__ outg)
{
  __shared__ char arena[32 * 1024];
  char* aS0 = arena;                 // L1 A dbuf: 2 x 8 KB fp16
  char* aS1 = arena + 8 * 1024;
  char* hL  = arena;                 // hidden: h [64][256] fp16, 32 KB overlay

  const int s    = blockIdx.y;
  const int row0 = blockIdx.x * TM;
  const int t    = threadIdx.x;
  const int lane = t & 63;
  const int w    = t >> 6;           // 0..3; wave w owns output cols w*64..+63
  const int g    = lane >> 4;
  const int l15  = lane & 15;

  const int gr   = row0 + (t >> 2);
  const bool valid = gr < NPER;
  const int grc  = valid ? gr : (NPER - 1);
  const float* fsrcT = feats + ((size_t)s * NPER + grc) * NF + (t & 3) * 16;
  const f16*   w1s   = w1t + (size_t)s * HID * NF;
  const f16*   w2s   = w2t + (size_t)s * HID * HID;
  const f16*   w3s   = w3t + (size_t)s * HID * HID;

  f32x4 acc[4][4];
  f16x8 bfA[8], bfB[8];
  zero_acc(acc);

  // ===== L1 prologue: A(0) staged; pa holds chunks 1,2; B(0) in flight =====
  float4 paA[4], paB[4];
  load_pa(paA, fsrcT, 0);
  load_b64(bfA, w1s, 0, NF, w, g, l15);
  load_pa(paB, fsrcT, 1);
  stage_feat64(aS0, paA, t);         // compiler waits paA's 4 loads only
  load_pa(paA, fsrcT, 2);
  WAIT_LGKM(); BARRIER();

  // ===== L1: 16 phases, KC=64, dbuf A (reg-staged), reg-dbuf B =====
  L1_PH(0,  aS0, aS1, bfA, bfB, paB, 1, 1);   // stage A1(paB), pa<-3
  L1_PH(1,  aS1, aS0, bfB, bfA, paA, 1, 1);   // stage A2(paA), pa<-4
  L1_PH(2,  aS0, aS1, bfA, bfB, paB, 1, 1);
  L1_PH(3,  aS1, aS0, bfB, bfA, paA, 1, 1);
  L1_PH(4,  aS0, aS1, bfA, bfB, paB, 1, 1);
  L1_PH(5,  aS1, aS0, bfB, bfA, paA, 1, 1);
  L1_PH(6,  aS0, aS1, bfA, bfB, paB, 1, 1);
  L1_PH(7,  aS1, aS0, bfB, bfA, paA, 1, 1);
  L1_PH(8,  aS0, aS1, bfA, bfB, paB, 1, 1);
  L1_PH(9,  aS1, aS0, bfB, bfA, paA, 1, 1);
  L1_PH(10, aS0, aS1, bfA, bfB, paB, 1, 1);
  L1_PH(11, aS1, aS0, bfB, bfA, paA, 1, 1);
  L1_PH(12, aS0, aS1, bfA, bfB, paB, 1, 1);   // pa(15) -> paB
  L1_PH(13, aS1, aS0, bfB, bfA, paA, 0, 1);   // stage A14(paA); no more pa
  L1_PH(14, aS0, aS1, bfA, bfB, paB, 0, 1);   // stage A15(paB); B15 -> bfB
  { // phase 15: compute aS1/bfB; early-issue W2 chunk 0 into bfA
    load_b64(bfA, w2s, 0, HID, w, g, l15);
    mfma64_ab(acc, aS1, bfB, g, l15);
    WAIT_LGKM(); BARRIER();
  }

  // ===== L1 -> L2: write h over dead A buffers =====
  silu_store(acc, b1g + s * HID, hL, w, lane);
  zero_acc(acc);
  WAIT_LGKM(); BARRIER();

  // ===== Layer 2: 4 chunks KC=64, barrier-free, reg-dbuf B =====
  load_b64(bfB, w2s, 1, HID, w, g, l15);  mfma64_h(acc, hL, 0, bfA, g, l15);
  load_b64(bfA, w2s, 2, HID, w, g, l15);  mfma64_h(acc, hL, 1, bfB, g, l15);
  load_b64(bfB, w2s, 3, HID, w, g, l15);  mfma64_h(acc, hL, 2, bfA, g, l15);
  load_b64(bfA, w3s, 0, HID, w, g, l15);  mfma64_h(acc, hL, 3, bfB, g, l15);
  BARRIER();                         // all waves done reading hL
  silu_store(acc, b2g + s * HID, hL, w, lane);
  zero_acc(acc);
  WAIT_LGKM(); BARRIER();            // hL published

  // ===== Layer 3: 4 chunks, barrier-free =====
  load_b64(bfB, w3s, 1, HID, w, g, l15);  mfma64_h(acc, hL, 0, bfA, g, l15);
  load_b64(bfA, w3s, 2, HID, w, g, l15);  mfma64_h(acc, hL, 1, bfB, g, l15);
  load_b64(bfB, w3s, 3, HID, w, g, l15);  mfma64_h(acc, hL, 2, bfA, g, l15);
                                          mfma64_h(acc, hL, 3, bfB, g, l15);
  BARRIER();
  silu_store(acc, b3g + s * HID, hL, w, lane);
  WAIT_LGKM(); BARRIER();

  // ===== Layer 4: e = h @ W4 + b4; segment-sum via atomicAdd =====
  {
    const int row = t >> 2;
    const int q   = t & 3;
    const float* w4 = w4g + s * HID;
    float sum = 0.f;
    #pragma unroll
    for (int j8 = 0; j8 < 64; j8 += 8) {
      const int k = q * 64 + j8;
      f16x8 hv = *(const f16x8*)(hL + (((row * HID + k) * 2) ^ ((row & 7) << 4)));
      float4 wa = *(const float4*)(w4 + k);
      float4 wb = *(const float4*)(w4 + k + 4);
      sum += (float)hv[0] * wa.x + (float)hv[1] * wa.y + (float)hv[2] * wa.z + (float)hv[3] * wa.w
           + (float)hv[4] * wb.x + (float)hv[5] * wb.y + (float)hv[6] * wb.z + (float)hv[7] * wb.w;
    }
    sum += __shfl_xor(sum, 1);
    sum += __shfl_xor(sum, 2);
    if (q == 0 && valid) {
      atomicAdd(&outg[sidxg[s * NPER + gr]], sum + b4g[s]);
    }
  }
}

// ---------------------------------------------------------------------------
extern "C" void kernel_launch(void* const* d_in, const int* in_sizes, int n_in,
                              void* d_out, int out_size, void* d_ws, size_t ws_size,
                              hipStream_t stream)
{
  const float* feats = (const float*)d_in[0];
  const float* W1    = (const float*)d_in[1];
  const float* b1    = (const float*)d_in[2];
  const float* W2    = (const float*)d_in[3];
  const float* b2    = (const float*)d_in[4];
  const float* W3    = (const float*)d_in[5];
  const float* b3    = (const float*)d_in[6];
  const float* W4    = (const float*)d_in[7];
  const float* b4    = (const float*)d_in[8];
  const int*   sidx  = (const int*)d_in[9];
  float* out = (float*)d_out;

  f16* w1t = (f16*)d_ws;                              // [S][256][1024] fp16
  f16* w2t = w1t + (size_t)S_ * HID * NF;             // [S][256][256]  fp16
  f16* w3t = w2t + (size_t)S_ * HID * HID;            // [S][256][256]  fp16

  hipMemsetAsync(d_out, 0, NSTRUCT * sizeof(float), stream);
  transpose_all_kernel<<<dim3(16, 4, 12), 256, 0, stream>>>(W1, W2, W3, w1t, w2t, w3t);
  mlp_fused_kernel<<<dim3((NPER + TM - 1) / TM, S_), 256, 0, stream>>>(
      feats, b1, b2, b3, W4, b4, sidx, w1t, w2t, w3t, out);
}

// Round 4
// 136.859 us; speedup vs baseline: 2.1356x; 1.0420x over previous
//
#include <hip/hip_runtime.h>

typedef _Float16 f16;
typedef __attribute__((ext_vector_type(8))) _Float16 f16x8;
typedef __attribute__((ext_vector_type(4))) float f32x4;
typedef unsigned int u32;

#define S_      4
#define NPER    12500
#define NF      1024
#define HID     256
#define NSTRUCT 500
#define TM      64

#define WAIT_LGKM() asm volatile("s_waitcnt lgkmcnt(0)" ::: "memory")
#define SCHED0()    __builtin_amdgcn_sched_barrier(0)
#define BARRIER()   do { __builtin_amdgcn_s_barrier(); SCHED0(); } while (0)

// ---------------------------------------------------------------------------
// Fused weight transpose + fp32->fp16 (all 3 layers, 1 launch) -- unchanged.
// ---------------------------------------------------------------------------
__global__ __launch_bounds__(256) void transpose_all_kernel(
    const float* __restrict__ W1, const float* __restrict__ W2,
    const float* __restrict__ W3,
    f16* __restrict__ w1t, f16* __restrict__ w2t, f16* __restrict__ w3t)
{
  const int z = blockIdx.z;            // layer*4 + species
  const int layer = z >> 2, sp = z & 3;
  const float* in; f16* out; int K;
  if (layer == 0)      { in = W1; out = w1t; K = NF;  }
  else if (layer == 1) { in = W2; out = w2t; K = HID; }
  else                 { in = W3; out = w3t; K = HID; }
  if (blockIdx.x * 64 >= K) return;

  __shared__ float tile[64][65];
  const float* inp = in + (size_t)sp * K * HID;
  f16* outp = out + (size_t)sp * K * HID;
  const int k0 = blockIdx.x * 64;
  const int n0 = blockIdx.y * 64;
  const int t = threadIdx.x;
  {
    const int lk = t >> 2;
    const int nq = (t & 3) * 16;
    const float* src = inp + (size_t)(k0 + lk) * HID + n0 + nq;
    #pragma unroll
    for (int i = 0; i < 4; ++i) {
      float4 v = *(const float4*)(src + i * 4);
      tile[lk][nq + i * 4 + 0] = v.x;
      tile[lk][nq + i * 4 + 1] = v.y;
      tile[lk][nq + i * 4 + 2] = v.z;
      tile[lk][nq + i * 4 + 3] = v.w;
    }
  }
  __syncthreads();
  {
    const int ln = t >> 2;
    const int kq = (t & 3) * 16;
    f16* dst = outp + (size_t)(n0 + ln) * K + k0 + kq;
    f16x8 a, b;
    #pragma unroll
    for (int j = 0; j < 8; ++j) a[j] = (f16)tile[kq + j][ln];
    #pragma unroll
    for (int j = 0; j < 8; ++j) b[j] = (f16)tile[kq + 8 + j][ln];
    *(f16x8*)dst = a;
    *(f16x8*)(dst + 8) = b;
  }
}

// ---------------------------------------------------------------------------
// Fused MLP R11 = R10 mechanics at 2x thread-level parallelism:
//  - 512 threads / 8 waves per block; wave w owns output cols w*32..+31.
//  - Per-wave work halves (16 MFMA/phase, 4 B-frags, acc[4][2]); raw live
//    VGPRs ~80 -> __launch_bounds__(512,4) caps at 128 => 2 blocks/CU
//    = 16 waves/CU = 4 waves/SIMD (2.8x R10's residency).
//  - Same proven pieces: pa fp32 regs 3-deep -> fp16 ds_write (XOR 8-slot
//    layout), B L2->regs dbuf, barrier-free hidden layers, compiler-counted
//    vm waits, 32 KB arena (A dbuf 2x8KB; hL 32KB overlay).
// ---------------------------------------------------------------------------

__device__ __forceinline__ void zero_acc(f32x4 (&acc)[4][2]) {
  #pragma unroll
  for (int a = 0; a < 4; ++a)
    #pragma unroll
    for (int b = 0; b < 2; ++b)
      #pragma unroll
      for (int j = 0; j < 4; ++j) acc[a][b][j] = 0.f;
}

// B fragments L2 -> regs: 4 x 16B per lane per KC=64 chunk.
// frag(ks,bt): col nn = w*32+bt*16+l15, k = c*64 + ks*32 + g*8 .. +7.
__device__ __forceinline__ void load_b64(f16x8 (&bf)[4], const f16* wsrc, int c,
                                         int K, int w, int g, int l15)
{
  #pragma unroll
  for (int ks = 0; ks < 2; ++ks)
    #pragma unroll
    for (int bt = 0; bt < 2; ++bt) {
      const int nn = w * 32 + bt * 16 + l15;
      bf[ks * 2 + bt] = *(const f16x8*)(wsrc + (size_t)nn * K + c * 64 + (ks * 4 + g) * 8);
    }
}

// Features prefetch: thread handles row t>>3, k-slot t&7 (8 floats).
__device__ __forceinline__ void load_pa(float4 (&pa)[2], const float* fsrcT, int c)
{
  pa[0] = *(const float4*)(fsrcT + c * 64);
  pa[1] = *(const float4*)(fsrcT + c * 64 + 4);
}

// Features chunk [64 r][64 k] fp32->fp16 into aS. Row = 128B = 8 slots of
// 16B; phys slot p at row r holds logical k-slot p^(r&7). One ds_write/thr.
__device__ __forceinline__ void stage_feat64(char* aS, const float4 (&pa)[2], int t)
{
  const int r = t >> 3;
  f16x8 hv;
  hv[0]=(f16)pa[0].x; hv[1]=(f16)pa[0].y; hv[2]=(f16)pa[0].z; hv[3]=(f16)pa[0].w;
  hv[4]=(f16)pa[1].x; hv[5]=(f16)pa[1].y; hv[6]=(f16)pa[1].z; hv[7]=(f16)pa[1].w;
  const int slog = t & 7;
  const int p = slog ^ (r & 7);
  *(f16x8*)(aS + r * 128 + p * 16) = hv;
}

// L1 compute: one KC=64 chunk, A from LDS (proven layout), B regs. 16 MFMA.
__device__ __forceinline__ void mfma64_ab(f32x4 (&acc)[4][2], const char* aS,
                                          const f16x8 (&bf)[4], int g, int l15)
{
  #pragma unroll
  for (int ks = 0; ks < 2; ++ks) {
    f16x8 af[4];
    #pragma unroll
    for (int at = 0; at < 4; ++at) {
      const int rr = at * 16 + l15;
      const int p  = (ks * 4 + g) ^ (rr & 7);
      af[at] = *(const f16x8*)(aS + rr * 128 + p * 16);
    }
    #pragma unroll
    for (int at = 0; at < 4; ++at)
      #pragma unroll
      for (int bt = 0; bt < 2; ++bt)
        acc[at][bt] = __builtin_amdgcn_mfma_f32_16x16x32_f16(af[at], bf[ks*2+bt], acc[at][bt], 0, 0, 0);
  }
}

// Hidden compute: KC=64 chunk, A = hL fp16 (xor (row&7)<<4 layout), B regs.
__device__ __forceinline__ void mfma64_h(f32x4 (&acc)[4][2], const char* hL, int cH,
                                         const f16x8 (&bf)[4], int g, int l15)
{
  #pragma unroll
  for (int ks = 0; ks < 2; ++ks) {
    f16x8 af[4];
    #pragma unroll
    for (int at = 0; at < 4; ++at) {
      const int rr = at * 16 + l15;
      af[at] = *(const f16x8*)(hL + ((rr * 512 + cH * 128 + ks * 64 + g * 16) ^ ((rr & 7) << 4)));
    }
    #pragma unroll
    for (int at = 0; at < 4; ++at)
      #pragma unroll
      for (int bt = 0; bt < 2; ++bt)
        acc[at][bt] = __builtin_amdgcn_mfma_f32_16x16x32_f16(af[at], bf[ks*2+bt], acc[at][bt], 0, 0, 0);
  }
}

__device__ __forceinline__ void silu_store(f32x4 (&acc)[4][2],
                                           const float* __restrict__ bias,
                                           char* hL, int w, int lane)
{
  const int g = lane >> 4, l15 = lane & 15;
  #pragma unroll
  for (int bt = 0; bt < 2; ++bt) {
    const int col = w * 32 + bt * 16 + l15;
    const float b = bias[col];
    #pragma unroll
    for (int at = 0; at < 4; ++at) {
      #pragma unroll
      for (int j = 0; j < 4; ++j) {
        const int row = at * 16 + g * 4 + j;   // m89-verified C/D mapping
        float x = acc[at][bt][j] + b;
        x = x * __builtin_amdgcn_rcpf(1.f + __expf(-x));
        *(f16*)(hL + (((row * HID + col) * 2) ^ ((row & 7) << 4))) = (f16)x;
      }
    }
  }
}

// Steady L1 phase: stage A(c+1) from pa (1 ds_write/thr), load B(c+1)->regs,
// refill pa with chunk c+3, compute chunk c, lgkm-drain, barrier.
#define L1_PH(c, AScur, ASstg, BFcur, BFnxt, PAset, DOPA, DOB)  \
  do {                                                           \
    stage_feat64(ASstg, PAset, t);                               \
    if (DOB)  load_b64(BFnxt, w1s, (c) + 1, NF, w, g, l15);      \
    if (DOPA) load_pa(PAset, fsrcT, (c) + 3);                    \
    mfma64_ab(acc, AScur, BFcur, g, l15);                        \
    WAIT_LGKM(); BARRIER();                                      \
  } while (0)

__global__ __launch_bounds__(512, 4) void mlp_fused_kernel(
    const float* __restrict__ feats,
    const float* __restrict__ b1g,
    const float* __restrict__ b2g,
    const float* __restrict__ b3g,
    const float* __restrict__ w4g,
    const float* __restrict__ b4g,
    const int*   __restrict__ sidxg,
    const f16*   __restrict__ w1t,
    const f16*   __restrict__ w2t,
    const f16*   __restrict__ w3t,
    float*       __restrict__ outg)
{
  __shared__ char arena[32 * 1024];
  char* aS0 = arena;                 // L1 A dbuf: 2 x 8 KB fp16
  char* aS1 = arena + 8 * 1024;
  char* hL  = arena;                 // hidden: h [64][256] fp16, 32 KB overlay

  const int s    = blockIdx.y;
  const int row0 = blockIdx.x * TM;
  const int t    = threadIdx.x;
  const int lane = t & 63;
  const int w    = t >> 6;           // 0..7; wave w owns output cols w*32..+31
  const int g    = lane >> 4;
  const int l15  = lane & 15;

  const int gr   = row0 + (t >> 3);  // staging/L4 row of this thread
  const bool valid = gr < NPER;
  const int grc  = valid ? gr : (NPER - 1);
  const float* fsrcT = feats + ((size_t)s * NPER + grc) * NF + (t & 7) * 8;
  const f16*   w1s   = w1t + (size_t)s * HID * NF;
  const f16*   w2s   = w2t + (size_t)s * HID * HID;
  const f16*   w3s   = w3t + (size_t)s * HID * HID;

  f32x4 acc[4][2];
  f16x8 bfA[4], bfB[4];
  zero_acc(acc);

  // ===== L1 prologue: A(0) staged; pa holds chunks 1,2; B(0) in flight =====
  float4 paA[2], paB[2];
  load_pa(paA, fsrcT, 0);
  load_b64(bfA, w1s, 0, NF, w, g, l15);
  load_pa(paB, fsrcT, 1);
  stage_feat64(aS0, paA, t);         // compiler waits paA's 2 loads only
  load_pa(paA, fsrcT, 2);
  WAIT_LGKM(); BARRIER();

  // ===== L1: 16 phases, KC=64, dbuf A (reg-staged), reg-dbuf B =====
  L1_PH(0,  aS0, aS1, bfA, bfB, paB, 1, 1);   // stage A1(paB), pa<-3
  L1_PH(1,  aS1, aS0, bfB, bfA, paA, 1, 1);   // stage A2(paA), pa<-4
  L1_PH(2,  aS0, aS1, bfA, bfB, paB, 1, 1);
  L1_PH(3,  aS1, aS0, bfB, bfA, paA, 1, 1);
  L1_PH(4,  aS0, aS1, bfA, bfB, paB, 1, 1);
  L1_PH(5,  aS1, aS0, bfB, bfA, paA, 1, 1);
  L1_PH(6,  aS0, aS1, bfA, bfB, paB, 1, 1);
  L1_PH(7,  aS1, aS0, bfB, bfA, paA, 1, 1);
  L1_PH(8,  aS0, aS1, bfA, bfB, paB, 1, 1);
  L1_PH(9,  aS1, aS0, bfB, bfA, paA, 1, 1);
  L1_PH(10, aS0, aS1, bfA, bfB, paB, 1, 1);
  L1_PH(11, aS1, aS0, bfB, bfA, paA, 1, 1);
  L1_PH(12, aS0, aS1, bfA, bfB, paB, 1, 1);   // pa(15) -> paB
  L1_PH(13, aS1, aS0, bfB, bfA, paA, 0, 1);   // stage A14(paA); no more pa
  L1_PH(14, aS0, aS1, bfA, bfB, paB, 0, 1);   // stage A15(paB); B15 -> bfB
  { // phase 15: compute aS1/bfB; early-issue W2 chunk 0 into bfA
    load_b64(bfA, w2s, 0, HID, w, g, l15);
    mfma64_ab(acc, aS1, bfB, g, l15);
    WAIT_LGKM(); BARRIER();
  }

  // ===== L1 -> L2: write h over dead A buffers =====
  silu_store(acc, b1g + s * HID, hL, w, lane);
  zero_acc(acc);
  WAIT_LGKM(); BARRIER();

  // ===== Layer 2: 4 chunks KC=64, barrier-free, reg-dbuf B =====
  load_b64(bfB, w2s, 1, HID, w, g, l15);  mfma64_h(acc, hL, 0, bfA, g, l15);
  load_b64(bfA, w2s, 2, HID, w, g, l15);  mfma64_h(acc, hL, 1, bfB, g, l15);
  load_b64(bfB, w2s, 3, HID, w, g, l15);  mfma64_h(acc, hL, 2, bfA, g, l15);
  load_b64(bfA, w3s, 0, HID, w, g, l15);  mfma64_h(acc, hL, 3, bfB, g, l15);
  BARRIER();                         // all waves done reading hL
  silu_store(acc, b2g + s * HID, hL, w, lane);
  zero_acc(acc);
  WAIT_LGKM(); BARRIER();            // hL published

  // ===== Layer 3: 4 chunks, barrier-free =====
  load_b64(bfB, w3s, 1, HID, w, g, l15);  mfma64_h(acc, hL, 0, bfA, g, l15);
  load_b64(bfA, w3s, 2, HID, w, g, l15);  mfma64_h(acc, hL, 1, bfB, g, l15);
  load_b64(bfB, w3s, 3, HID, w, g, l15);  mfma64_h(acc, hL, 2, bfA, g, l15);
                                          mfma64_h(acc, hL, 3, bfB, g, l15);
  BARRIER();
  silu_store(acc, b3g + s * HID, hL, w, lane);
  WAIT_LGKM(); BARRIER();

  // ===== Layer 4: e = h @ W4 + b4; segment-sum via atomicAdd =====
  {
    const int row = t >> 3;
    const int q   = t & 7;
    const float* w4 = w4g + s * HID;
    float sum = 0.f;
    #pragma unroll
    for (int j8 = 0; j8 < 32; j8 += 8) {
      const int k = q * 32 + j8;
      f16x8 hv = *(const f16x8*)(hL + (((row * HID + k) * 2) ^ ((row & 7) << 4)));
      float4 wa = *(const float4*)(w4 + k);
      float4 wb = *(const float4*)(w4 + k + 4);
      sum += (float)hv[0] * wa.x + (float)hv[1] * wa.y + (float)hv[2] * wa.z + (float)hv[3] * wa.w
           + (float)hv[4] * wb.x + (float)hv[5] * wb.y + (float)hv[6] * wb.z + (float)hv[7] * wb.w;
    }
    sum += __shfl_xor(sum, 1);
    sum += __shfl_xor(sum, 2);
    sum += __shfl_xor(sum, 4);
    if (q == 0 && valid) {
      atomicAdd(&outg[sidxg[s * NPER + gr]], sum + b4g[s]);
    }
  }
}

// ---------------------------------------------------------------------------
extern "C" void kernel_launch(void* const* d_in, const int* in_sizes, int n_in,
                              void* d_out, int out_size, void* d_ws, size_t ws_size,
                              hipStream_t stream)
{
  const float* feats = (const float*)d_in[0];
  const float* W1    = (const float*)d_in[1];
  const float* b1    = (const float*)d_in[2];
  const float* W2    = (const float*)d_in[3];
  const float* b2    = (const float*)d_in[4];
  const float* W3    = (const float*)d_in[5];
  const float* b3    = (const float*)d_in[6];
  const float* W4    = (const float*)d_in[7];
  const float* b4    = (const float*)d_in[8];
  const int*   sidx  = (const int*)d_in[9];
  float* out = (float*)d_out;

  f16* w1t = (f16*)d_ws;                              // [S][256][1024] fp16
  f16* w2t = w1t + (size_t)S_ * HID * NF;             // [S][256][256]  fp16
  f16* w3t = w2t + (size_t)S_ * HID * HID;            // [S][256][256]  fp16

  hipMemsetAsync(d_out, 0, NSTRUCT * sizeof(float), stream);
  transpose_all_kernel<<<dim3(16, 4, 12), 256, 0, stream>>>(W1, W2, W3, w1t, w2t, w3t);
  mlp_fused_kernel<<<dim3((NPER + TM - 1) / TM, S_), 512, 0, stream>>>(
      feats, b1, b2, b3, W4, b4, sidx, w1t, w2t, w3t, out);
}